// Round 1
// baseline (173.453 us; speedup 1.0000x reference)
//
#include <hip/hip_runtime.h>

#define GX 192
#define GY 96
#define GZ 192
#define GRP (GY*GZ)            // 18432 (y,z) groups
#define NVOX (GX*GRP)          // 3538944 voxels
#define NMAT 8

// workspace byte offsets
#define WS_MVP    0                        // 16 floats
#define WS_DEPTH  64                       // GRP u32 depth bits
#define WS_CNT    (WS_DEPTH + GRP*4)       // GRP u32 valid counts
#define WS_SEL    (WS_CNT + GRP*4)         // 4 u32: T, R, (pad)
#define WS_TLIST  (WS_SEL + 16)            // 256 u32 tied group ids (sorted)
#define WS_TPREF  (WS_TLIST + 1024)        // GX u32 exclusive prefix of tied-valid per x
#define WS_NTIED  (WS_TPREF + GX*4)        // 1 u32
#define WS_BYTES  (WS_NTIED + 16)

// Replicate reference fp32 arithmetic exactly:
//   clip_c = fma(cz, M[c][2], fma(cy, M[c][1], cx*M[c][0])) + M[c][3]
// (intrinsics pin rounding; -ffp-contract cannot touch them)
__device__ __forceinline__ bool voxel_valid(int x, int g,
                                            const float* __restrict__ occL,
                                            const float* __restrict__ M,
                                            float* __restrict__ occ_out)
{
    int y = g / GZ;
    int z = g - y * GZ;
    float cx = (float)(2 * x - 191);
    float cy = (float)(2 * y + 1);
    float cz = (float)(2 * z - 191);

    float logit = occL[(size_t)x * GRP + g];
    float occ = 1.0f / (1.0f + expf(-logit));
    *occ_out = occ;
    if (!(occ > 0.01f)) return false;

    float c0 = __fadd_rn(__fmaf_rn(cz, M[2],  __fmaf_rn(cy, M[1],  __fmul_rn(cx, M[0]))),  M[3]);
    float c1 = __fadd_rn(__fmaf_rn(cz, M[6],  __fmaf_rn(cy, M[5],  __fmul_rn(cx, M[4]))),  M[7]);
    float c2 = __fadd_rn(__fmaf_rn(cz, M[10], __fmaf_rn(cy, M[9],  __fmul_rn(cx, M[8]))),  M[11]);
    float c3 = __fadd_rn(__fmaf_rn(cz, M[14], __fmaf_rn(cy, M[13], __fmul_rn(cx, M[12]))), M[15]);

    float w  = fmaxf(c3, 1e-6f);
    float nx = c0 / w;
    float ny = c1 / w;
    float nz = c2 / w;
    return (nx >= -1.0f) && (nx <= 1.0f) &&
           (ny >= -1.0f) && (ny <= 1.0f) &&
           (nz >= -1.0f) && (nz <= 1.0f);
}

// mvp = proj @ view. Zero structure of proj makes the result independent of
// summation order / fma-vs-mul (each entry is one product or product+add).
__global__ void k_prep(const float* __restrict__ view,
                       const float* __restrict__ proj,
                       float* __restrict__ mvp)
{
    int t = threadIdx.x;
    if (t < 16) {
        int r = t >> 2, c = t & 3;
        float acc = 0.0f;
        for (int k = 0; k < 4; ++k)
            acc = __fadd_rn(acc, __fmul_rn(proj[r * 4 + k], view[k * 4 + c]));
        mvp[t] = acc;
    }
}

// depth per (y,z) group; x-term contributes +/-0 (view[8] == -0.0), use x=0 seed.
__global__ void k_depth(const float* __restrict__ view,
                        unsigned* __restrict__ depthBits)
{
    int g = blockIdx.x * 256 + threadIdx.x;
    if (g >= GRP) return;
    int y = g / GZ;
    int z = g - y * GZ;
    float cy = (float)(2 * y + 1);
    float cz = (float)(2 * z - 191);
    float seed = __fmul_rn(-191.0f, view[8]);
    float vz = __fadd_rn(__fmaf_rn(cz, view[10], __fmaf_rn(cy, view[9], seed)), view[11]);
    float d  = fmaxf(-vz, 0.0f);
    depthBits[g] = __float_as_uint(d);   // d >= 0: bits are order-monotone
}

__global__ void k_count(const float* __restrict__ occL,
                        const float* __restrict__ mvp,
                        unsigned* __restrict__ cnt)
{
    int i = blockIdx.x * 256 + threadIdx.x;
    if (i >= NVOX) return;
    int x = i / GRP;
    int g = i - x * GRP;
    float occ;
    if (voxel_valid(x, g, occL, mvp, &occ))
        atomicAdd(&cnt[g], 1u);
}

// weighted radix-select (4 x 8 bits) over group depth bits to find the
// K-th smallest depth among valid voxels. sel[0]=T bits, sel[1]=R quota at T.
__global__ void k_select(const unsigned* __restrict__ depthBits,
                         const unsigned* __restrict__ cnt,
                         unsigned* __restrict__ sel,
                         const int* __restrict__ maxBlocksPtr)
{
    __shared__ unsigned hist[256];
    __shared__ unsigned s_prefix;
    __shared__ unsigned s_remK;
    __shared__ int s_done;
    int tid = threadIdx.x;
    unsigned K = (unsigned)maxBlocksPtr[0];
    if (tid == 0) { s_prefix = 0; s_remK = K; s_done = 0; }
    __syncthreads();

    for (int p = 0; p < 4; ++p) {
        hist[tid] = 0;
        __syncthreads();
        int shift = 24 - 8 * p;
        if (!s_done) {
            for (int g = tid; g < GRP; g += 256) {
                unsigned c = cnt[g];
                if (!c) continue;
                unsigned db = depthBits[g];
                if (p > 0 && (db >> (shift + 8)) != s_prefix) continue;
                atomicAdd(&hist[(db >> shift) & 255u], c);
            }
        }
        __syncthreads();
        if (tid == 0 && !s_done) {
            if (p == 0) {
                unsigned long long total = 0;
                for (int b = 0; b < 256; ++b) total += hist[b];
                if (total <= (unsigned long long)K) {
                    sel[0] = 0xFFFFFFFFu;   // keep all valid
                    sel[1] = 0x7FFFFFFFu;
                    s_done = 1;
                }
            }
            if (!s_done) {
                unsigned cum = 0;
                int b = 0;
                for (; b < 255; ++b) {
                    if (cum + hist[b] >= s_remK) break;
                    cum += hist[b];
                }
                s_prefix = (s_prefix << 8) | (unsigned)b;
                s_remK   = s_remK - cum;
            }
        }
        __syncthreads();
    }
    if (tid == 0 && !s_done) {
        sel[0] = s_prefix;
        sel[1] = s_remK;
    }
}

// Build sorted list of groups with depth bits == T, and exclusive prefix
// (over x) of valid tied voxels, for the index-order tie break.
__global__ void k_tied(const unsigned* __restrict__ depthBits,
                       const unsigned* __restrict__ sel,
                       const float* __restrict__ occL,
                       const float* __restrict__ mvp,
                       unsigned* __restrict__ tiedList,
                       unsigned* __restrict__ tiedPrefX,
                       unsigned* __restrict__ nTiedG)
{
    __shared__ unsigned s_list[256];
    __shared__ int s_n;
    __shared__ unsigned s_cntX[GX];
    int tid = threadIdx.x;
    unsigned T = sel[0];
    if (tid == 0) s_n = 0;
    if (tid < GX) s_cntX[tid] = 0;
    __syncthreads();

    for (int g = tid; g < GRP; g += 256) {
        if (depthBits[g] == T) {
            int idx = atomicAdd(&s_n, 1);
            if (idx < 256) s_list[idx] = (unsigned)g;
        }
    }
    __syncthreads();
    int n = min(s_n, 256);
    if (tid == 0) {
        for (int a = 1; a < n; ++a) {          // insertion sort (n is tiny)
            unsigned v = s_list[a];
            int b = a - 1;
            while (b >= 0 && s_list[b] > v) { s_list[b + 1] = s_list[b]; --b; }
            s_list[b + 1] = v;
        }
    }
    __syncthreads();

    int pairs = GX * n;
    for (int pr = tid; pr < pairs; pr += 256) {
        int x = pr / n;
        int s = pr - x * n;
        float occ;
        if (voxel_valid(x, (int)s_list[s], occL, mvp, &occ))
            atomicAdd(&s_cntX[x], 1u);
    }
    __syncthreads();

    if (tid == 0) {
        unsigned run = 0;
        for (int x = 0; x < GX; ++x) { tiedPrefX[x] = run; run += s_cntX[x]; }
        *nTiedG = (unsigned)n;
    }
    if (tid < n) tiedList[tid] = s_list[tid];
}

__global__ void k_out(const float* __restrict__ occL,
                      const float* __restrict__ matL,
                      const float* __restrict__ mvp,
                      const unsigned* __restrict__ depthBits,
                      const unsigned* __restrict__ sel,
                      const unsigned* __restrict__ tiedList,
                      const unsigned* __restrict__ tiedPrefX,
                      const unsigned* __restrict__ nTiedPtr,
                      float* __restrict__ out)
{
    int i = blockIdx.x * 256 + threadIdx.x;
    if (i >= NVOX) return;
    int x = i / GRP;
    int g = i - x * GRP;

    float occ;
    bool valid = voxel_valid(x, g, occL, mvp, &occ);
    bool keep = false;
    if (valid) {
        unsigned T  = sel[0];
        unsigned db = depthBits[g];
        if (db < T) {
            keep = true;
        } else if (db == T) {
            unsigned R = sel[1];
            unsigned rank = tiedPrefX[x];
            int n = (int)*nTiedPtr;
            for (int s = 0; s < n; ++s) {
                unsigned gs = tiedList[s];
                if (gs >= (unsigned)g) break;
                float o2;
                if (voxel_valid(x, (int)gs, occL, mvp, &o2)) ++rank;
            }
            keep = rank < R;
        }
    }

    float4 o0 = make_float4(0.f, 0.f, 0.f, 0.f);
    float4 o1 = make_float4(0.f, 0.f, 0.f, 0.f);
    if (keep) {
        const float4* mp = reinterpret_cast<const float4*>(matL) + (size_t)i * 2;
        float4 a = mp[0];
        float4 b = mp[1];
        float mx = fmaxf(fmaxf(fmaxf(a.x, a.y), fmaxf(a.z, a.w)),
                         fmaxf(fmaxf(b.x, b.y), fmaxf(b.z, b.w)));
        float e0 = expf(a.x - mx), e1 = expf(a.y - mx), e2 = expf(a.z - mx), e3 = expf(a.w - mx);
        float e4 = expf(b.x - mx), e5 = expf(b.y - mx), e6 = expf(b.z - mx), e7 = expf(b.w - mx);
        float s = ((e0 + e1) + (e2 + e3)) + ((e4 + e5) + (e6 + e7));
        float inv = occ / s;
        o0 = make_float4(e0 * inv, e1 * inv, e2 * inv, e3 * inv);
        o1 = make_float4(e4 * inv, e5 * inv, e6 * inv, e7 * inv);
    }
    float4* op = reinterpret_cast<float4*>(out) + (size_t)i * 2;
    op[0] = o0;
    op[1] = o1;
}

extern "C" void kernel_launch(void* const* d_in, const int* in_sizes, int n_in,
                              void* d_out, int out_size, void* d_ws, size_t ws_size,
                              hipStream_t stream)
{
    const float* occL = (const float*)d_in[0];
    const float* matL = (const float*)d_in[1];
    const float* view = (const float*)d_in[2];
    const float* proj = (const float*)d_in[3];
    const int*   mb   = (const int*)d_in[4];

    char* ws = (char*)d_ws;
    float*    mvp      = (float*)(ws + WS_MVP);
    unsigned* depthB   = (unsigned*)(ws + WS_DEPTH);
    unsigned* cnt      = (unsigned*)(ws + WS_CNT);
    unsigned* sel      = (unsigned*)(ws + WS_SEL);
    unsigned* tiedList = (unsigned*)(ws + WS_TLIST);
    unsigned* tiedPref = (unsigned*)(ws + WS_TPREF);
    unsigned* nTied    = (unsigned*)(ws + WS_NTIED);

    hipMemsetAsync(cnt, 0, GRP * sizeof(unsigned), stream);

    k_prep<<<1, 64, 0, stream>>>(view, proj, mvp);
    k_depth<<<GRP / 256, 256, 0, stream>>>(view, depthB);
    k_count<<<NVOX / 256, 256, 0, stream>>>(occL, mvp, cnt);
    k_select<<<1, 256, 0, stream>>>(depthB, cnt, sel, mb);
    k_tied<<<1, 256, 0, stream>>>(depthB, sel, occL, mvp, tiedList, tiedPref, nTied);
    k_out<<<NVOX / 256, 256, 0, stream>>>(occL, matL, mvp, depthB, sel,
                                          tiedList, tiedPref, nTied, (float*)d_out);
}

// Round 2
// 110.537 us; speedup vs baseline: 1.5692x; 1.5692x over previous
//
#include <hip/hip_runtime.h>

#define GX 192
#define GY 96
#define GZ 192
#define GRP (GY*GZ)            // 18432 (y,z) groups
#define NVOX (GX*GRP)          // 3538944 voxels
#define NMAT 8

// workspace byte offsets
#define WS_MVP    0                        // 16 floats
#define WS_DEPTH  64                       // GRP u32 depth bits
#define WS_CNT    (WS_DEPTH + GRP*4)       // GRP u32 valid counts      (memset 0)
#define WS_HIST   (WS_CNT + GRP*4)         // 4 passes x 256 u32 bins   (memset 0)
#define WS_STATE  (WS_HIST + 4096)         // prefix, remK, done, pad   (memset 0)
#define WS_SEL    (WS_STATE + 16)          // 2 u32: T, R
#define WS_TLIST  (WS_SEL + 16)            // 256 u32 tied group ids (sorted)
#define WS_TPREF  (WS_TLIST + 1024)        // GX u32 excl prefix of tied-valid per x
#define WS_NTIED  (WS_TPREF + GX*4)        // 1 u32
#define WS_ZERO_BYTES (GRP*4 + 4096 + 16)  // memset range starting at WS_CNT

// Replicate reference fp32 arithmetic exactly:
//   clip_c = fma(cz, M[c][2], fma(cy, M[c][1], cx*M[c][0])) + M[c][3]
__device__ __forceinline__ bool voxel_valid(int x, int g,
                                            const float* __restrict__ occL,
                                            const float* __restrict__ M,
                                            float* __restrict__ occ_out)
{
    int y = g / GZ;
    int z = g - y * GZ;
    float cx = (float)(2 * x - 191);
    float cy = (float)(2 * y + 1);
    float cz = (float)(2 * z - 191);

    float logit = occL[(size_t)x * GRP + g];
    float occ = 1.0f / (1.0f + expf(-logit));
    *occ_out = occ;
    if (!(occ > 0.01f)) return false;

    float c0 = __fadd_rn(__fmaf_rn(cz, M[2],  __fmaf_rn(cy, M[1],  __fmul_rn(cx, M[0]))),  M[3]);
    float c1 = __fadd_rn(__fmaf_rn(cz, M[6],  __fmaf_rn(cy, M[5],  __fmul_rn(cx, M[4]))),  M[7]);
    float c2 = __fadd_rn(__fmaf_rn(cz, M[10], __fmaf_rn(cy, M[9],  __fmul_rn(cx, M[8]))),  M[11]);
    float c3 = __fadd_rn(__fmaf_rn(cz, M[14], __fmaf_rn(cy, M[13], __fmul_rn(cx, M[12]))), M[15]);

    float w  = fmaxf(c3, 1e-6f);
    float nx = c0 / w;
    float ny = c1 / w;
    float nz = c2 / w;
    return (nx >= -1.0f) && (nx <= 1.0f) &&
           (ny >= -1.0f) && (ny <= 1.0f) &&
           (nz >= -1.0f) && (nz <= 1.0f);
}

__global__ void k_prep(const float* __restrict__ view,
                       const float* __restrict__ proj,
                       float* __restrict__ mvp)
{
    int t = threadIdx.x;
    if (t < 16) {
        int r = t >> 2, c = t & 3;
        float acc = 0.0f;
        for (int k = 0; k < 4; ++k)
            acc = __fadd_rn(acc, __fmul_rn(proj[r * 4 + k], view[k * 4 + c]));
        mvp[t] = acc;
    }
}

__global__ void k_depth(const float* __restrict__ view,
                        unsigned* __restrict__ depthBits)
{
    int g = blockIdx.x * 256 + threadIdx.x;
    if (g >= GRP) return;
    int y = g / GZ;
    int z = g - y * GZ;
    float cy = (float)(2 * y + 1);
    float cz = (float)(2 * z - 191);
    float seed = __fmul_rn(-191.0f, view[8]);
    float vz = __fadd_rn(__fmaf_rn(cz, view[10], __fmaf_rn(cy, view[9], seed)), view[11]);
    float d  = fmaxf(-vz, 0.0f);
    depthBits[g] = __float_as_uint(d);   // d >= 0: bits are order-monotone
}

__global__ void k_count(const float* __restrict__ occL,
                        const float* __restrict__ mvp,
                        unsigned* __restrict__ cnt)
{
    int i = blockIdx.x * 256 + threadIdx.x;
    if (i >= NVOX) return;
    int x = i / GRP;
    int g = i - x * GRP;
    float occ;
    if (voxel_valid(x, g, occL, mvp, &occ))
        atomicAdd(&cnt[g], 1u);
}

// wide weighted histogram for radix pass p (digit = bits [shift+7 : shift])
__global__ void k_hist(int p,
                       const unsigned* __restrict__ depthBits,
                       const unsigned* __restrict__ cnt,
                       const unsigned* __restrict__ state,
                       unsigned* __restrict__ hist)   // this pass's 256 bins
{
    __shared__ unsigned h[256];
    int tid = threadIdx.x;
    h[tid] = 0;
    __syncthreads();

    if (!(p > 0 && state[2])) {            // skip if already done
        int g = blockIdx.x * 256 + tid;
        if (g < GRP) {
            unsigned c = cnt[g];
            if (c) {
                unsigned db = depthBits[g];
                int shift = 24 - 8 * p;
                bool match = (p == 0) || ((db >> (shift + 8)) == state[0]);
                if (match)
                    atomicAdd(&h[(db >> shift) & 255u], c);
            }
        }
    }
    __syncthreads();
    if (h[tid])
        atomicAdd(&hist[tid], h[tid]);
}

// pick kernel: advance (prefix, remK) through this pass's histogram
__global__ void k_pick(int p,
                       const unsigned* __restrict__ hist,
                       unsigned* __restrict__ state,
                       unsigned* __restrict__ sel,
                       const int* __restrict__ maxBlocksPtr)
{
    __shared__ unsigned h[256];
    int tid = threadIdx.x;
    h[tid] = hist[tid];
    __syncthreads();

    if (tid != 0) return;
    if (p > 0 && state[2]) return;         // done at p==0: keep-all already set

    unsigned K = (unsigned)maxBlocksPtr[0];
    unsigned remK = (p == 0) ? K : state[1];

    if (p == 0) {
        unsigned long long total = 0;
        for (int b = 0; b < 256; ++b) total += h[b];
        if (total <= (unsigned long long)K) {
            sel[0] = 0xFFFFFFFFu;          // keep all valid
            sel[1] = 0x7FFFFFFFu;
            state[2] = 1u;
            return;
        }
    }

    unsigned cum = 0;
    int b = 0;
    for (; b < 255; ++b) {
        if (cum + h[b] >= remK) break;
        cum += h[b];
    }
    unsigned prefix = ((p == 0) ? 0u : state[0]);
    prefix = (prefix << 8) | (unsigned)b;
    remK   = remK - cum;

    if (p == 3) {
        sel[0] = prefix;
        sel[1] = remK;
    } else {
        state[0] = prefix;
        state[1] = remK;
    }
}

// Build sorted list of groups with depth bits == T, and exclusive prefix
// (over x) of valid tied voxels, for the index-order tie break.
__global__ void k_tied(const unsigned* __restrict__ depthBits,
                       const unsigned* __restrict__ sel,
                       const float* __restrict__ occL,
                       const float* __restrict__ mvp,
                       unsigned* __restrict__ tiedList,
                       unsigned* __restrict__ tiedPrefX,
                       unsigned* __restrict__ nTiedG)
{
    __shared__ unsigned s_list[256];
    __shared__ int s_n;
    __shared__ unsigned s_cntX[GX];
    int tid = threadIdx.x;
    unsigned T = sel[0];
    if (tid == 0) s_n = 0;
    if (tid < GX) s_cntX[tid] = 0;
    __syncthreads();

    for (int g = tid; g < GRP; g += 256) {
        if (depthBits[g] == T) {
            int idx = atomicAdd(&s_n, 1);
            if (idx < 256) s_list[idx] = (unsigned)g;
        }
    }
    __syncthreads();
    int n = min(s_n, 256);
    if (tid == 0) {
        for (int a = 1; a < n; ++a) {          // insertion sort (n is tiny)
            unsigned v = s_list[a];
            int b = a - 1;
            while (b >= 0 && s_list[b] > v) { s_list[b + 1] = s_list[b]; --b; }
            s_list[b + 1] = v;
        }
    }
    __syncthreads();

    int pairs = GX * n;
    for (int pr = tid; pr < pairs; pr += 256) {
        int x = pr / n;
        int s = pr - x * n;
        float occ;
        if (voxel_valid(x, (int)s_list[s], occL, mvp, &occ))
            atomicAdd(&s_cntX[x], 1u);
    }
    __syncthreads();

    if (tid == 0) {
        unsigned run = 0;
        for (int x = 0; x < GX; ++x) { tiedPrefX[x] = run; run += s_cntX[x]; }
        *nTiedG = (unsigned)n;
    }
    if (tid < n) tiedList[tid] = s_list[tid];
}

__global__ void k_out(const float* __restrict__ occL,
                      const float* __restrict__ matL,
                      const float* __restrict__ mvp,
                      const unsigned* __restrict__ depthBits,
                      const unsigned* __restrict__ sel,
                      const unsigned* __restrict__ tiedList,
                      const unsigned* __restrict__ tiedPrefX,
                      const unsigned* __restrict__ nTiedPtr,
                      float* __restrict__ out)
{
    int i = blockIdx.x * 256 + threadIdx.x;
    if (i >= NVOX) return;
    int x = i / GRP;
    int g = i - x * GRP;

    float occ;
    bool valid = voxel_valid(x, g, occL, mvp, &occ);
    bool keep = false;
    if (valid) {
        unsigned T  = sel[0];
        unsigned db = depthBits[g];
        if (db < T) {
            keep = true;
        } else if (db == T) {
            unsigned R = sel[1];
            unsigned rank = tiedPrefX[x];
            int n = (int)*nTiedPtr;
            for (int s = 0; s < n; ++s) {
                unsigned gs = tiedList[s];
                if (gs >= (unsigned)g) break;
                float o2;
                if (voxel_valid(x, (int)gs, occL, mvp, &o2)) ++rank;
            }
            keep = rank < R;
        }
    }

    float4 o0 = make_float4(0.f, 0.f, 0.f, 0.f);
    float4 o1 = make_float4(0.f, 0.f, 0.f, 0.f);
    if (keep) {
        const float4* mp = reinterpret_cast<const float4*>(matL) + (size_t)i * 2;
        float4 a = mp[0];
        float4 b = mp[1];
        float mx = fmaxf(fmaxf(fmaxf(a.x, a.y), fmaxf(a.z, a.w)),
                         fmaxf(fmaxf(b.x, b.y), fmaxf(b.z, b.w)));
        float e0 = expf(a.x - mx), e1 = expf(a.y - mx), e2 = expf(a.z - mx), e3 = expf(a.w - mx);
        float e4 = expf(b.x - mx), e5 = expf(b.y - mx), e6 = expf(b.z - mx), e7 = expf(b.w - mx);
        float s = ((e0 + e1) + (e2 + e3)) + ((e4 + e5) + (e6 + e7));
        float inv = occ / s;
        o0 = make_float4(e0 * inv, e1 * inv, e2 * inv, e3 * inv);
        o1 = make_float4(e4 * inv, e5 * inv, e6 * inv, e7 * inv);
    }
    float4* op = reinterpret_cast<float4*>(out) + (size_t)i * 2;
    op[0] = o0;
    op[1] = o1;
}

extern "C" void kernel_launch(void* const* d_in, const int* in_sizes, int n_in,
                              void* d_out, int out_size, void* d_ws, size_t ws_size,
                              hipStream_t stream)
{
    const float* occL = (const float*)d_in[0];
    const float* matL = (const float*)d_in[1];
    const float* view = (const float*)d_in[2];
    const float* proj = (const float*)d_in[3];
    const int*   mb   = (const int*)d_in[4];

    char* ws = (char*)d_ws;
    float*    mvp      = (float*)(ws + WS_MVP);
    unsigned* depthB   = (unsigned*)(ws + WS_DEPTH);
    unsigned* cnt      = (unsigned*)(ws + WS_CNT);
    unsigned* hist     = (unsigned*)(ws + WS_HIST);
    unsigned* state    = (unsigned*)(ws + WS_STATE);
    unsigned* sel      = (unsigned*)(ws + WS_SEL);
    unsigned* tiedList = (unsigned*)(ws + WS_TLIST);
    unsigned* tiedPref = (unsigned*)(ws + WS_TPREF);
    unsigned* nTied    = (unsigned*)(ws + WS_NTIED);

    // zero cnt + all 4 hist buffers + state in one memset
    hipMemsetAsync(cnt, 0, WS_ZERO_BYTES, stream);

    k_prep<<<1, 64, 0, stream>>>(view, proj, mvp);
    k_depth<<<GRP / 256, 256, 0, stream>>>(view, depthB);
    k_count<<<NVOX / 256, 256, 0, stream>>>(occL, mvp, cnt);

    for (int p = 0; p < 4; ++p) {
        k_hist<<<GRP / 256, 256, 0, stream>>>(p, depthB, cnt, state, hist + p * 256);
        k_pick<<<1, 256, 0, stream>>>(p, hist + p * 256, state, sel, mb);
    }

    k_tied<<<1, 256, 0, stream>>>(depthB, sel, occL, mvp, tiedList, tiedPref, nTied);
    k_out<<<NVOX / 256, 256, 0, stream>>>(occL, matL, mvp, depthB, sel,
                                          tiedList, tiedPref, nTied, (float*)d_out);
}

// Round 3
// 107.727 us; speedup vs baseline: 1.6101x; 1.0261x over previous
//
#include <hip/hip_runtime.h>

#define GX 192
#define GY 96
#define GZ 192
#define GRP (GY*GZ)            // 18432 (y,z) groups
#define NVOX (GX*GRP)          // 3538944 voxels
#define NMAT 8

// workspace byte offsets
#define WS_MVP    0                        // 16 floats
#define WS_DEPTH  64                       // GRP u32 depth bits
#define WS_CNT    (WS_DEPTH + GRP*4)       // GRP u32 valid counts   (zeroed in k_depth)
#define WS_HIST   (WS_CNT + GRP*4)         // 4 passes x 256 u32 bins (zeroed in k_depth)
#define WS_STATE  (WS_HIST + 4096)         // prefix, remK, done, pad (zeroed in k_depth)
#define WS_SEL    (WS_STATE + 16)          // 2 u32: T, R
#define WS_TLIST  (WS_SEL + 16)            // 256 u32 tied group ids (sorted)
#define WS_TPREF  (WS_TLIST + 1024)        // GX u32 excl prefix of tied-valid per x
#define WS_NTIED  (WS_TPREF + GX*4)        // 1 u32

// Replicate reference fp32 arithmetic exactly:
//   clip_c = fma(cz, M[c][2], fma(cy, M[c][1], cx*M[c][0])) + M[c][3]
__device__ __forceinline__ bool voxel_valid(int x, int g,
                                            const float* __restrict__ occL,
                                            const float* __restrict__ M,
                                            float* __restrict__ occ_out)
{
    int y = g / GZ;
    int z = g - y * GZ;
    float cx = (float)(2 * x - 191);
    float cy = (float)(2 * y + 1);
    float cz = (float)(2 * z - 191);

    float logit = occL[(size_t)x * GRP + g];
    float occ = 1.0f / (1.0f + expf(-logit));
    *occ_out = occ;
    if (!(occ > 0.01f)) return false;

    float c0 = __fadd_rn(__fmaf_rn(cz, M[2],  __fmaf_rn(cy, M[1],  __fmul_rn(cx, M[0]))),  M[3]);
    float c1 = __fadd_rn(__fmaf_rn(cz, M[6],  __fmaf_rn(cy, M[5],  __fmul_rn(cx, M[4]))),  M[7]);
    float c2 = __fadd_rn(__fmaf_rn(cz, M[10], __fmaf_rn(cy, M[9],  __fmul_rn(cx, M[8]))),  M[11]);
    float c3 = __fadd_rn(__fmaf_rn(cz, M[14], __fmaf_rn(cy, M[13], __fmul_rn(cx, M[12]))), M[15]);

    float w  = fmaxf(c3, 1e-6f);
    float nx = c0 / w;
    float ny = c1 / w;
    float nz = c2 / w;
    return (nx >= -1.0f) && (nx <= 1.0f) &&
           (ny >= -1.0f) && (ny <= 1.0f) &&
           (nz >= -1.0f) && (nz <= 1.0f);
}

__global__ void k_prep(const float* __restrict__ view,
                       const float* __restrict__ proj,
                       float* __restrict__ mvp)
{
    int t = threadIdx.x;
    if (t < 16) {
        int r = t >> 2, c = t & 3;
        float acc = 0.0f;
        for (int k = 0; k < 4; ++k)
            acc = __fadd_rn(acc, __fmul_rn(proj[r * 4 + k], view[k * 4 + c]));
        mvp[t] = acc;
    }
}

// depth per (y,z) group; also zeroes cnt + hist + state (runs before all consumers)
__global__ void k_depth(const float* __restrict__ view,
                        unsigned* __restrict__ depthBits,
                        unsigned* __restrict__ cnt,
                        unsigned* __restrict__ histState)  // 4*256 bins + 4 state words
{
    int g = blockIdx.x * 256 + threadIdx.x;
    if (g >= GRP) return;
    cnt[g] = 0;
    if (g < 1024 + 4) histState[g] = 0;

    int y = g / GZ;
    int z = g - y * GZ;
    float cy = (float)(2 * y + 1);
    float cz = (float)(2 * z - 191);
    float seed = __fmul_rn(-191.0f, view[8]);
    float vz = __fadd_rn(__fmaf_rn(cz, view[10], __fmaf_rn(cy, view[9], seed)), view[11]);
    float d  = fmaxf(-vz, 0.0f);
    depthBits[g] = __float_as_uint(d);   // d >= 0: bits are order-monotone
}

__global__ void k_count(const float* __restrict__ occL,
                        const float* __restrict__ mvp,
                        unsigned* __restrict__ cnt)
{
    int i = blockIdx.x * 256 + threadIdx.x;
    if (i >= NVOX) return;
    int x = i / GRP;
    int g = i - x * GRP;
    float occ;
    if (voxel_valid(x, g, occL, mvp, &occ))
        atomicAdd(&cnt[g], 1u);
}

// wide weighted histogram for radix pass p (digit = bits [shift+7 : shift])
__global__ void k_hist(int p,
                       const unsigned* __restrict__ depthBits,
                       const unsigned* __restrict__ cnt,
                       const unsigned* __restrict__ state,
                       unsigned* __restrict__ hist)   // this pass's 256 bins
{
    __shared__ unsigned h[256];
    int tid = threadIdx.x;
    h[tid] = 0;
    __syncthreads();

    if (!(p > 0 && state[2])) {            // skip if already done
        int g = blockIdx.x * 256 + tid;
        if (g < GRP) {
            unsigned c = cnt[g];
            if (c) {
                unsigned db = depthBits[g];
                int shift = 24 - 8 * p;
                bool match = (p == 0) || ((db >> (shift + 8)) == state[0]);
                if (match)
                    atomicAdd(&h[(db >> shift) & 255u], c);
            }
        }
    }
    __syncthreads();
    if (h[tid])
        atomicAdd(&hist[tid], h[tid]);
}

// pick kernel: advance (prefix, remK) through this pass's histogram
__global__ void k_pick(int p,
                       const unsigned* __restrict__ hist,
                       unsigned* __restrict__ state,
                       unsigned* __restrict__ sel,
                       const int* __restrict__ maxBlocksPtr)
{
    __shared__ unsigned h[256];
    int tid = threadIdx.x;
    h[tid] = hist[tid];
    __syncthreads();

    if (tid != 0) return;
    if (p > 0 && state[2]) return;         // done at p==0: keep-all already set

    unsigned K = (unsigned)maxBlocksPtr[0];
    unsigned remK = (p == 0) ? K : state[1];

    if (p == 0) {
        unsigned long long total = 0;
        for (int b = 0; b < 256; ++b) total += h[b];
        if (total <= (unsigned long long)K) {
            sel[0] = 0xFFFFFFFFu;          // keep all valid
            sel[1] = 0x7FFFFFFFu;
            state[2] = 1u;
            return;
        }
        state[2] = 0u;                     // always write: no stale flag across replays
    }

    unsigned cum = 0;
    int b = 0;
    for (; b < 255; ++b) {
        if (cum + h[b] >= remK) break;
        cum += h[b];
    }
    unsigned prefix = ((p == 0) ? 0u : state[0]);
    prefix = (prefix << 8) | (unsigned)b;
    remK   = remK - cum;

    if (p == 3) {
        sel[0] = prefix;
        sel[1] = remK;
    } else {
        state[0] = prefix;
        state[1] = remK;
    }
}

// Build sorted list of groups with depth bits == T, and exclusive prefix
// (over x) of valid tied voxels, for the index-order tie break.
__global__ void k_tied(const unsigned* __restrict__ depthBits,
                       const unsigned* __restrict__ sel,
                       const float* __restrict__ occL,
                       const float* __restrict__ mvp,
                       unsigned* __restrict__ tiedList,
                       unsigned* __restrict__ tiedPrefX,
                       unsigned* __restrict__ nTiedG)
{
    __shared__ unsigned s_list[256];
    __shared__ int s_n;
    __shared__ unsigned s_cntX[GX];
    int tid = threadIdx.x;
    unsigned T = sel[0];
    if (tid == 0) s_n = 0;
    if (tid < GX) s_cntX[tid] = 0;
    __syncthreads();

    for (int g = tid; g < GRP; g += 256) {
        if (depthBits[g] == T) {
            int idx = atomicAdd(&s_n, 1);
            if (idx < 256) s_list[idx] = (unsigned)g;
        }
    }
    __syncthreads();
    int n = min(s_n, 256);
    if (tid == 0) {
        for (int a = 1; a < n; ++a) {          // insertion sort (n is tiny)
            unsigned v = s_list[a];
            int b = a - 1;
            while (b >= 0 && s_list[b] > v) { s_list[b + 1] = s_list[b]; --b; }
            s_list[b + 1] = v;
        }
    }
    __syncthreads();

    int pairs = GX * n;
    for (int pr = tid; pr < pairs; pr += 256) {
        int x = pr / n;
        int s = pr - x * n;
        float occ;
        if (voxel_valid(x, (int)s_list[s], occL, mvp, &occ))
            atomicAdd(&s_cntX[x], 1u);
    }
    __syncthreads();

    if (tid == 0) {
        unsigned run = 0;
        for (int x = 0; x < GX; ++x) { tiedPrefX[x] = run; run += s_cntX[x]; }
        *nTiedG = (unsigned)n;
    }
    if (tid < n) tiedList[tid] = s_list[tid];
}

__global__ void k_out(const float* __restrict__ occL,
                      const float* __restrict__ matL,
                      const float* __restrict__ mvp,
                      const unsigned* __restrict__ depthBits,
                      const unsigned* __restrict__ sel,
                      const unsigned* __restrict__ tiedList,
                      const unsigned* __restrict__ tiedPrefX,
                      const unsigned* __restrict__ nTiedPtr,
                      float* __restrict__ out)
{
    int i = blockIdx.x * 256 + threadIdx.x;
    if (i >= NVOX) return;
    int x = i / GRP;
    int g = i - x * GRP;

    float occ;
    bool valid = voxel_valid(x, g, occL, mvp, &occ);
    bool keep = false;
    if (valid) {
        unsigned T  = sel[0];
        unsigned db = depthBits[g];
        if (db < T) {
            keep = true;
        } else if (db == T) {
            unsigned R = sel[1];
            unsigned rank = tiedPrefX[x];
            int n = (int)*nTiedPtr;
            for (int s = 0; s < n; ++s) {
                unsigned gs = tiedList[s];
                if (gs >= (unsigned)g) break;
                float o2;
                if (voxel_valid(x, (int)gs, occL, mvp, &o2)) ++rank;
            }
            keep = rank < R;
        }
    }

    float4 o0 = make_float4(0.f, 0.f, 0.f, 0.f);
    float4 o1 = make_float4(0.f, 0.f, 0.f, 0.f);
    if (keep) {
        const float4* mp = reinterpret_cast<const float4*>(matL) + (size_t)i * 2;
        float4 a = mp[0];
        float4 b = mp[1];
        float mx = fmaxf(fmaxf(fmaxf(a.x, a.y), fmaxf(a.z, a.w)),
                         fmaxf(fmaxf(b.x, b.y), fmaxf(b.z, b.w)));
        float e0 = expf(a.x - mx), e1 = expf(a.y - mx), e2 = expf(a.z - mx), e3 = expf(a.w - mx);
        float e4 = expf(b.x - mx), e5 = expf(b.y - mx), e6 = expf(b.z - mx), e7 = expf(b.w - mx);
        float s = ((e0 + e1) + (e2 + e3)) + ((e4 + e5) + (e6 + e7));
        float inv = occ / s;
        o0 = make_float4(e0 * inv, e1 * inv, e2 * inv, e3 * inv);
        o1 = make_float4(e4 * inv, e5 * inv, e6 * inv, e7 * inv);
    }
    float4* op = reinterpret_cast<float4*>(out) + (size_t)i * 2;
    op[0] = o0;
    op[1] = o1;
}

extern "C" void kernel_launch(void* const* d_in, const int* in_sizes, int n_in,
                              void* d_out, int out_size, void* d_ws, size_t ws_size,
                              hipStream_t stream)
{
    const float* occL = (const float*)d_in[0];
    const float* matL = (const float*)d_in[1];
    const float* view = (const float*)d_in[2];
    const float* proj = (const float*)d_in[3];
    const int*   mb   = (const int*)d_in[4];

    char* ws = (char*)d_ws;
    float*    mvp      = (float*)(ws + WS_MVP);
    unsigned* depthB   = (unsigned*)(ws + WS_DEPTH);
    unsigned* cnt      = (unsigned*)(ws + WS_CNT);
    unsigned* hist     = (unsigned*)(ws + WS_HIST);   // + state contiguous after
    unsigned* state    = (unsigned*)(ws + WS_STATE);
    unsigned* sel      = (unsigned*)(ws + WS_SEL);
    unsigned* tiedList = (unsigned*)(ws + WS_TLIST);
    unsigned* tiedPref = (unsigned*)(ws + WS_TPREF);
    unsigned* nTied    = (unsigned*)(ws + WS_NTIED);

    k_prep<<<1, 64, 0, stream>>>(view, proj, mvp);
    k_depth<<<GRP / 256, 256, 0, stream>>>(view, depthB, cnt, hist);
    k_count<<<NVOX / 256, 256, 0, stream>>>(occL, mvp, cnt);

    for (int p = 0; p < 4; ++p) {
        k_hist<<<GRP / 256, 256, 0, stream>>>(p, depthB, cnt, state, hist + p * 256);
        k_pick<<<1, 256, 0, stream>>>(p, hist + p * 256, state, sel, mb);
    }

    k_tied<<<1, 256, 0, stream>>>(depthB, sel, occL, mvp, tiedList, tiedPref, nTied);
    k_out<<<NVOX / 256, 256, 0, stream>>>(occL, matL, mvp, depthB, sel,
                                          tiedList, tiedPref, nTied, (float*)d_out);
}

// Round 4
// 77.792 us; speedup vs baseline: 2.2297x; 1.3848x over previous
//
#include <hip/hip_runtime.h>

#define GX 192
#define GY 96
#define GZ 192
#define GRP (GY*GZ)            // 18432 (y,z) groups
#define NVOX (GX*GRP)          // 3538944 voxels

#define NXC 3                  // x-chunks in count kernel
#define XCW (GX/NXC)           // 64
#define GBLK (GRP/256)         // 72 blocks per chunk

#define K2T 1024               // select kernel threads
#define GPT (GRP/K2T)          // 18 groups per thread
#define WBINS 4096             // window chunk bins (16-bit pass)
#define BPT (WBINS/K2T)        // 4 bins per thread

// workspace byte offsets
#define WS_MVP    0                        // 16 floats
#define WS_DEPTH  64                       // GRP u32 depth bits
#define WS_CNT3   (WS_DEPTH + GRP*4)       // NXC x GRP u32 partial counts
#define WS_SEL    (WS_CNT3 + NXC*GRP*4)    // 2 u32: T, R
#define WS_TLIST  (WS_SEL + 16)            // 256 u32 tied group ids (sorted)
#define WS_TPREF  (WS_TLIST + 1024)        // GX u32 excl prefix of tied-valid per x
#define WS_NTIED  (WS_TPREF + GX*4)        // 1 u32

// Replicate reference fp32 arithmetic exactly:
//   clip_c = fma(cz, M[c][2], fma(cy, M[c][1], cx*M[c][0])) + M[c][3]
__device__ __forceinline__ bool voxel_valid(int x, int g,
                                            const float* __restrict__ occL,
                                            const float* M,
                                            float* occ_out)
{
    int y = g / GZ;
    int z = g - y * GZ;
    float cx = (float)(2 * x - 191);
    float cy = (float)(2 * y + 1);
    float cz = (float)(2 * z - 191);

    float logit = occL[(size_t)x * GRP + g];
    float occ = 1.0f / (1.0f + expf(-logit));
    *occ_out = occ;
    if (!(occ > 0.01f)) return false;

    float c0 = __fadd_rn(__fmaf_rn(cz, M[2],  __fmaf_rn(cy, M[1],  __fmul_rn(cx, M[0]))),  M[3]);
    float c1 = __fadd_rn(__fmaf_rn(cz, M[6],  __fmaf_rn(cy, M[5],  __fmul_rn(cx, M[4]))),  M[7]);
    float c2 = __fadd_rn(__fmaf_rn(cz, M[10], __fmaf_rn(cy, M[9],  __fmul_rn(cx, M[8]))),  M[11]);
    float c3 = __fadd_rn(__fmaf_rn(cz, M[14], __fmaf_rn(cy, M[13], __fmul_rn(cx, M[12]))), M[15]);

    float w  = fmaxf(c3, 1e-6f);
    float nx = c0 / w;
    float ny = c1 / w;
    float nz = c2 / w;
    return (nx >= -1.0f) && (nx <= 1.0f) &&
           (ny >= -1.0f) && (ny <= 1.0f) &&
           (nz >= -1.0f) && (nz <= 1.0f);
}

__device__ __forceinline__ void compute_mvp_lds(const float* view, const float* proj,
                                                float* s_mvp, int tid)
{
    if (tid < 16) {
        int r = tid >> 2, c = tid & 3;
        float acc = 0.0f;
        for (int k = 0; k < 4; ++k)
            acc = __fadd_rn(acc, __fmul_rn(proj[r * 4 + k], view[k * 4 + c]));
        s_mvp[tid] = acc;
    }
}

// K1: mvp (block 0 -> ws), depth bits (xc==0), partial valid counts per x-chunk.
// grid = NXC * GBLK = 216 blocks of 256. No atomics, no pre-zeroing needed.
__global__ __launch_bounds__(256) void k_prep_count(
    const float* __restrict__ view, const float* __restrict__ proj,
    const float* __restrict__ occL,
    float* __restrict__ mvpOut,
    unsigned* __restrict__ depthBits,
    unsigned* __restrict__ cnt3)
{
    __shared__ float s_mvp[16];
    int tid = threadIdx.x;
    compute_mvp_lds(view, proj, s_mvp, tid);
    __syncthreads();

    int b  = blockIdx.x;
    int gb = b % GBLK;
    int xc = b / GBLK;
    int g  = gb * 256 + tid;

    if (b == 0 && tid < 16) mvpOut[tid] = s_mvp[tid];

    if (xc == 0) {
        int y = g / GZ;
        int z = g - y * GZ;
        float cy = (float)(2 * y + 1);
        float cz = (float)(2 * z - 191);
        float seed = __fmul_rn(-191.0f, view[8]);
        float vz = __fadd_rn(__fmaf_rn(cz, view[10], __fmaf_rn(cy, view[9], seed)), view[11]);
        float d  = fmaxf(-vz, 0.0f);
        depthBits[g] = __float_as_uint(d);   // d >= 0: bits order-monotone
    }

    unsigned c = 0;
    int x0 = xc * XCW;
    for (int x = x0; x < x0 + XCW; ++x) {
        float occ;
        if (voxel_valid(x, g, occL, s_mvp, &occ)) ++c;
    }
    cnt3[(size_t)xc * GRP + g] = c;
}

// K2: full weighted selection + tied-group prep in ONE block of 1024 threads.
// Integer-identical to the verified 4x8-bit radix walk, restructured as:
//   windowed 16-bit pass (chunks of 4096 bins over [min16,max16]) + 2x 8-bit.
__global__ __launch_bounds__(1024) void k_select(
    const float* __restrict__ view, const float* __restrict__ proj,
    const float* __restrict__ occL,
    const unsigned* __restrict__ depthBits,
    const unsigned* __restrict__ cnt3,
    const int* __restrict__ maxBlocksPtr,
    unsigned* __restrict__ sel,
    unsigned* __restrict__ tiedList,
    unsigned* __restrict__ tiedPrefX,
    unsigned* __restrict__ nTiedG)
{
    __shared__ float s_mvp[16];
    __shared__ unsigned s_h[WBINS];      // 16 KB hist (also reused for 256-bin passes)
    __shared__ unsigned s_scan[K2T];     // 4 KB scan buffer
    __shared__ unsigned s_wT[16], s_wMn[16], s_wMx[16];
    __shared__ unsigned s_tot, s_mn, s_mx;
    __shared__ unsigned s_found, s_prefix, s_remK;
    __shared__ unsigned s_list[256];
    __shared__ int s_n;
    __shared__ unsigned s_cntX[GX];

    int tid = threadIdx.x;
    compute_mvp_lds(view, proj, s_mvp, tid);

    // ---- load all (depth, cnt) pairs into registers (static indexing) ----
    unsigned d[GPT], c[GPT];
    #pragma unroll
    for (int k = 0; k < GPT; ++k) {
        int g = tid + k * K2T;
        d[k] = depthBits[g];
        c[k] = cnt3[g] + cnt3[GRP + g] + cnt3[2 * GRP + g];
    }

    // ---- reduce: total valid, min/max of top-16 depth bits (weighted) ----
    unsigned tot = 0, mn = 0xFFFFFFFFu, mx = 0;
    #pragma unroll
    for (int k = 0; k < GPT; ++k) {
        tot += c[k];
        if (c[k]) {
            unsigned hi = d[k] >> 16;
            mn = min(mn, hi);
            mx = max(mx, hi);
        }
    }
    for (int m = 1; m < 64; m <<= 1) {
        tot += (unsigned)__shfl_xor((int)tot, m);
        mn = min(mn, (unsigned)__shfl_xor((int)mn, m));
        mx = max(mx, (unsigned)__shfl_xor((int)mx, m));
    }
    int wid = tid >> 6;
    if ((tid & 63) == 0) { s_wT[wid] = tot; s_wMn[wid] = mn; s_wMx[wid] = mx; }
    __syncthreads();
    if (tid == 0) {
        unsigned t2 = 0, m2 = 0xFFFFFFFFu, x2 = 0;
        for (int w = 0; w < 16; ++w) {
            t2 += s_wT[w]; m2 = min(m2, s_wMn[w]); x2 = max(x2, s_wMx[w]);
        }
        s_tot = t2; s_mn = m2; s_mx = x2;
        s_found = 0;
    }
    __syncthreads();
    unsigned K = (unsigned)maxBlocksPtr[0];
    tot = s_tot; mn = s_mn; mx = s_mx;

    if (tot <= K) {                         // keep all valid
        if (tid == 0) {
            sel[0] = 0xFFFFFFFFu;
            sel[1] = 0x7FFFFFFFu;
            *nTiedG = 0u;
        }
        return;                             // uniform exit, no barriers after
    }

    // ---- pass A: 16-bit windowed histogram, chunks of WBINS ----
    unsigned remK = K;
    unsigned prefix = 0;
    unsigned span = mx - mn + 1u;
    unsigned nchunks = (span + WBINS - 1u) / WBINS;
    for (unsigned ch = 0; ch < nchunks; ++ch) {
        unsigned base = mn + ch * WBINS;
        #pragma unroll
        for (int j = 0; j < BPT; ++j) s_h[tid + j * K2T] = 0;
        __syncthreads();
        #pragma unroll
        for (int k = 0; k < GPT; ++k) {
            if (c[k]) {
                unsigned hi = d[k] >> 16;
                if (hi >= base && hi < base + WBINS)
                    atomicAdd(&s_h[hi - base], c[k]);
            }
        }
        __syncthreads();
        unsigned ps = 0;
        #pragma unroll
        for (int j = 0; j < BPT; ++j) ps += s_h[tid * BPT + j];
        s_scan[tid] = ps;
        __syncthreads();
        for (int off = 1; off < K2T; off <<= 1) {
            unsigned v = s_scan[tid];
            unsigned a = (tid >= off) ? s_scan[tid - off] : 0u;
            __syncthreads();
            s_scan[tid] = v + a;
            __syncthreads();
        }
        unsigned incl = s_scan[tid];
        unsigned chunkTot = s_scan[K2T - 1];
        unsigned excl = incl - ps;
        if (remK <= chunkTot && excl < remK && remK <= incl) {
            unsigned cum = excl;
            #pragma unroll
            for (int j = 0; j < BPT; ++j) {
                unsigned hv = s_h[tid * BPT + j];
                if (cum < remK && remK <= cum + hv) {
                    s_found  = 1u;
                    s_prefix = base + (unsigned)(tid * BPT + j);
                    s_remK   = remK - cum;
                }
                cum += hv;
            }
        }
        __syncthreads();
        if (s_found) { prefix = s_prefix; remK = s_remK; break; }
        remK -= chunkTot;                   // uniform
        __syncthreads();
    }

    // ---- passes B, C: 8-bit refine (bits 15..8 then 7..0) ----
    for (int p = 0; p < 2; ++p) {
        int matchShift = (p == 0) ? 16 : 8;
        int digitShift = (p == 0) ? 8 : 0;
        if (tid < 256) s_h[tid] = 0;
        __syncthreads();
        #pragma unroll
        for (int k = 0; k < GPT; ++k) {
            if (c[k] && (d[k] >> matchShift) == prefix)
                atomicAdd(&s_h[(d[k] >> digitShift) & 255u], c[k]);
        }
        __syncthreads();
        unsigned ps = (tid < 256) ? s_h[tid] : 0u;
        s_scan[tid] = ps;
        __syncthreads();
        for (int off = 1; off < K2T; off <<= 1) {
            unsigned v = s_scan[tid];
            unsigned a = (tid >= off) ? s_scan[tid - off] : 0u;
            __syncthreads();
            s_scan[tid] = v + a;
            __syncthreads();
        }
        unsigned incl = s_scan[tid];
        unsigned excl = incl - ps;
        if (excl < remK && remK <= incl) {   // unique crossing thread (tid<256)
            s_prefix = (prefix << 8) | (unsigned)tid;
            s_remK   = remK - excl;
        }
        __syncthreads();
        prefix = s_prefix; remK = s_remK;
        __syncthreads();
    }
    unsigned T = prefix;                     // final threshold depth bits
    unsigned R = remK;                       // quota at exactly T

    // ---- tied groups: list (sorted), per-x valid prefix ----
    if (tid == 0) s_n = 0;
    for (int x = tid; x < GX; x += K2T) s_cntX[x] = 0;
    __syncthreads();
    #pragma unroll
    for (int k = 0; k < GPT; ++k) {
        if (d[k] == T) {
            int idx = atomicAdd(&s_n, 1);
            if (idx < 256) s_list[idx] = (unsigned)(tid + k * K2T);
        }
    }
    __syncthreads();
    int n = min(s_n, 256);
    if (tid == 0) {
        for (int a = 1; a < n; ++a) {        // insertion sort (n tiny)
            unsigned v = s_list[a];
            int b = a - 1;
            while (b >= 0 && s_list[b] > v) { s_list[b + 1] = s_list[b]; --b; }
            s_list[b + 1] = v;
        }
    }
    __syncthreads();
    int pairs = GX * n;
    for (int pr = tid; pr < pairs; pr += K2T) {
        int x = pr / n;
        int s = pr - x * n;
        float occ;
        if (voxel_valid(x, (int)s_list[s], occL, s_mvp, &occ))
            atomicAdd(&s_cntX[x], 1u);
    }
    __syncthreads();
    if (tid == 0) {
        unsigned run = 0;
        for (int x = 0; x < GX; ++x) { tiedPrefX[x] = run; run += s_cntX[x]; }
        *nTiedG = (unsigned)n;
        sel[0] = T;
        sel[1] = R;
    }
    if (tid < n) tiedList[tid] = s_list[tid];
}

__global__ void k_out(const float* __restrict__ occL,
                      const float* __restrict__ matL,
                      const float* __restrict__ mvp,
                      const unsigned* __restrict__ depthBits,
                      const unsigned* __restrict__ sel,
                      const unsigned* __restrict__ tiedList,
                      const unsigned* __restrict__ tiedPrefX,
                      const unsigned* __restrict__ nTiedPtr,
                      float* __restrict__ out)
{
    int i = blockIdx.x * 256 + threadIdx.x;
    if (i >= NVOX) return;
    int x = i / GRP;
    int g = i - x * GRP;

    float occ;
    bool valid = voxel_valid(x, g, occL, mvp, &occ);
    bool keep = false;
    if (valid) {
        unsigned T  = sel[0];
        unsigned db = depthBits[g];
        if (db < T) {
            keep = true;
        } else if (db == T) {
            unsigned R = sel[1];
            unsigned rank = tiedPrefX[x];
            int n = (int)*nTiedPtr;
            for (int s = 0; s < n; ++s) {
                unsigned gs = tiedList[s];
                if (gs >= (unsigned)g) break;
                float o2;
                if (voxel_valid(x, (int)gs, occL, mvp, &o2)) ++rank;
            }
            keep = rank < R;
        }
    }

    float4 o0 = make_float4(0.f, 0.f, 0.f, 0.f);
    float4 o1 = make_float4(0.f, 0.f, 0.f, 0.f);
    if (keep) {
        const float4* mp = reinterpret_cast<const float4*>(matL) + (size_t)i * 2;
        float4 a = mp[0];
        float4 b = mp[1];
        float mx = fmaxf(fmaxf(fmaxf(a.x, a.y), fmaxf(a.z, a.w)),
                         fmaxf(fmaxf(b.x, b.y), fmaxf(b.z, b.w)));
        float e0 = expf(a.x - mx), e1 = expf(a.y - mx), e2 = expf(a.z - mx), e3 = expf(a.w - mx);
        float e4 = expf(b.x - mx), e5 = expf(b.y - mx), e6 = expf(b.z - mx), e7 = expf(b.w - mx);
        float s = ((e0 + e1) + (e2 + e3)) + ((e4 + e5) + (e6 + e7));
        float inv = occ / s;
        o0 = make_float4(e0 * inv, e1 * inv, e2 * inv, e3 * inv);
        o1 = make_float4(e4 * inv, e5 * inv, e6 * inv, e7 * inv);
    }
    float4* op = reinterpret_cast<float4*>(out) + (size_t)i * 2;
    op[0] = o0;
    op[1] = o1;
}

extern "C" void kernel_launch(void* const* d_in, const int* in_sizes, int n_in,
                              void* d_out, int out_size, void* d_ws, size_t ws_size,
                              hipStream_t stream)
{
    const float* occL = (const float*)d_in[0];
    const float* matL = (const float*)d_in[1];
    const float* view = (const float*)d_in[2];
    const float* proj = (const float*)d_in[3];
    const int*   mb   = (const int*)d_in[4];

    char* ws = (char*)d_ws;
    float*    mvp      = (float*)(ws + WS_MVP);
    unsigned* depthB   = (unsigned*)(ws + WS_DEPTH);
    unsigned* cnt3     = (unsigned*)(ws + WS_CNT3);
    unsigned* sel      = (unsigned*)(ws + WS_SEL);
    unsigned* tiedList = (unsigned*)(ws + WS_TLIST);
    unsigned* tiedPref = (unsigned*)(ws + WS_TPREF);
    unsigned* nTied    = (unsigned*)(ws + WS_NTIED);

    k_prep_count<<<NXC * GBLK, 256, 0, stream>>>(view, proj, occL, mvp, depthB, cnt3);
    k_select<<<1, K2T, 0, stream>>>(view, proj, occL, depthB, cnt3, mb,
                                    sel, tiedList, tiedPref, nTied);
    k_out<<<NVOX / 256, 256, 0, stream>>>(occL, matL, mvp, depthB, sel,
                                          tiedList, tiedPref, nTied, (float*)d_out);
}

// Round 5
// 64.107 us; speedup vs baseline: 2.7057x; 1.2135x over previous
//
#include <hip/hip_runtime.h>

#define GX 192
#define GY 96
#define GZ 192
#define GRP (GY*GZ)            // 18432 (y,z) groups
#define NVOX (GX*GRP)          // 3538944 voxels

#define NXC 12                 // x-chunks in count kernel
#define XCW (GX/NXC)           // 16 voxels per thread
#define GBLK (GRP/256)         // 72 blocks per chunk
#define CSTR 16                // bytes per group in u8 count buffer (12 used, 4 pad)

#define K2T 1024               // select kernel threads
#define GPT (GRP/K2T)          // 18 groups per thread
#define WBINS 4096             // window chunk bins (16-bit pass)
#define BPT (WBINS/K2T)        // 4 bins per thread

// workspace byte offsets
#define WS_MVP    0                        // 16 floats
#define WS_DEPTH  64                       // GRP u32 depth bits
#define WS_CNT8   (WS_DEPTH + GRP*4)       // GRP x CSTR u8 partial counts
#define WS_SEL    (WS_CNT8 + GRP*CSTR)     // 2 u32: T, R
#define WS_TLIST  (WS_SEL + 16)            // 256 u32 tied group ids (sorted)
#define WS_TPREF  (WS_TLIST + 1024)        // GX u32 excl prefix of tied-valid per x
#define WS_NTIED  (WS_TPREF + GX*4)        // 1 u32

typedef float f4 __attribute__((ext_vector_type(4)));

// Replicate reference fp32 arithmetic exactly:
//   clip_c = fma(cz, M[c][2], fma(cy, M[c][1], cx*M[c][0])) + M[c][3]
__device__ __forceinline__ bool voxel_valid(int x, int g,
                                            const float* __restrict__ occL,
                                            const float* M,
                                            float* occ_out)
{
    int y = g / GZ;
    int z = g - y * GZ;
    float cx = (float)(2 * x - 191);
    float cy = (float)(2 * y + 1);
    float cz = (float)(2 * z - 191);

    float logit = occL[(size_t)x * GRP + g];
    float occ = 1.0f / (1.0f + expf(-logit));
    *occ_out = occ;
    if (!(occ > 0.01f)) return false;

    float c0 = __fadd_rn(__fmaf_rn(cz, M[2],  __fmaf_rn(cy, M[1],  __fmul_rn(cx, M[0]))),  M[3]);
    float c1 = __fadd_rn(__fmaf_rn(cz, M[6],  __fmaf_rn(cy, M[5],  __fmul_rn(cx, M[4]))),  M[7]);
    float c2 = __fadd_rn(__fmaf_rn(cz, M[10], __fmaf_rn(cy, M[9],  __fmul_rn(cx, M[8]))),  M[11]);
    float c3 = __fadd_rn(__fmaf_rn(cz, M[14], __fmaf_rn(cy, M[13], __fmul_rn(cx, M[12]))), M[15]);

    float w  = fmaxf(c3, 1e-6f);
    float nx = c0 / w;
    float ny = c1 / w;
    float nz = c2 / w;
    return (nx >= -1.0f) && (nx <= 1.0f) &&
           (ny >= -1.0f) && (ny <= 1.0f) &&
           (nz >= -1.0f) && (nz <= 1.0f);
}

__device__ __forceinline__ void compute_mvp_lds(const float* view, const float* proj,
                                                float* s_mvp, int tid)
{
    if (tid < 16) {
        int r = tid >> 2, c = tid & 3;
        float acc = 0.0f;
        for (int k = 0; k < 4; ++k)
            acc = __fadd_rn(acc, __fmul_rn(proj[r * 4 + k], view[k * 4 + c]));
        s_mvp[tid] = acc;
    }
}

__device__ __forceinline__ unsigned wave_incl_scan(unsigned v, int lane)
{
    #pragma unroll
    for (int off = 1; off < 64; off <<= 1) {
        unsigned u = (unsigned)__shfl_up((int)v, off);
        if (lane >= off) v += u;
    }
    return v;
}

// K1: mvp (block 0 -> ws), depth bits (xc==0), u8 partial valid counts per x-chunk.
// grid = NXC * GBLK = 864 blocks of 256. No atomics, no pre-zeroing needed.
__global__ __launch_bounds__(256) void k_prep_count(
    const float* __restrict__ view, const float* __restrict__ proj,
    const float* __restrict__ occL,
    float* __restrict__ mvpOut,
    unsigned* __restrict__ depthBits,
    unsigned char* __restrict__ cnt8)
{
    __shared__ float s_mvp[16];
    int tid = threadIdx.x;
    compute_mvp_lds(view, proj, s_mvp, tid);
    __syncthreads();

    int b  = blockIdx.x;
    int gb = b % GBLK;
    int xc = b / GBLK;
    int g  = gb * 256 + tid;

    if (b == 0 && tid < 16) mvpOut[tid] = s_mvp[tid];

    if (xc == 0) {
        int y = g / GZ;
        int z = g - y * GZ;
        float cy = (float)(2 * y + 1);
        float cz = (float)(2 * z - 191);
        float seed = __fmul_rn(-191.0f, view[8]);
        float vz = __fadd_rn(__fmaf_rn(cz, view[10], __fmaf_rn(cy, view[9], seed)), view[11]);
        float d  = fmaxf(-vz, 0.0f);
        depthBits[g] = __float_as_uint(d);   // d >= 0: bits order-monotone
    }

    unsigned c = 0;
    int x0 = xc * XCW;
    for (int x = x0; x < x0 + XCW; ++x) {
        float occ;
        if (voxel_valid(x, g, occL, s_mvp, &occ)) ++c;
    }
    cnt8[(size_t)g * CSTR + xc] = (unsigned char)c;
}

// K2: full weighted selection + tied-group prep in ONE block of 1024 threads.
// Integer-identical to the verified radix walk: windowed 16-bit pass + 2x 8-bit,
// scans done hierarchically (wave shfl scan + wave offsets; 2 barriers/scan).
__global__ __launch_bounds__(1024) void k_select(
    const float* __restrict__ view, const float* __restrict__ proj,
    const float* __restrict__ occL,
    const unsigned* __restrict__ depthBits,
    const unsigned char* __restrict__ cnt8,
    const int* __restrict__ maxBlocksPtr,
    unsigned* __restrict__ sel,
    unsigned* __restrict__ tiedList,
    unsigned* __restrict__ tiedPrefX,
    unsigned* __restrict__ nTiedG)
{
    __shared__ float s_mvp[16];
    __shared__ unsigned s_h[WBINS];      // 16 KB hist (reused for 256-bin passes)
    __shared__ unsigned s_w[16];         // wave partials / offsets
    __shared__ unsigned s_wT[16], s_wMn[16], s_wMx[16];
    __shared__ unsigned s_tot, s_mn, s_mx, s_chTot;
    __shared__ unsigned s_found, s_prefix, s_remK;
    __shared__ unsigned s_list[256];
    __shared__ int s_n;
    __shared__ unsigned s_cntX[GX];

    int tid  = threadIdx.x;
    int lane = tid & 63;
    int wid  = tid >> 6;
    compute_mvp_lds(view, proj, s_mvp, tid);

    // ---- load all (depth, cnt) pairs into registers (static indexing) ----
    unsigned d[GPT], c[GPT];
    #pragma unroll
    for (int k = 0; k < GPT; ++k) {
        int g = tid + k * K2T;
        d[k] = depthBits[g];
        const unsigned* cp = (const unsigned*)(cnt8 + (size_t)g * CSTR);
        unsigned w0 = cp[0], w1 = cp[1], w2 = cp[2];
        unsigned s = (w0 & 255u) + ((w0 >> 8) & 255u) + ((w0 >> 16) & 255u) + (w0 >> 24);
        s += (w1 & 255u) + ((w1 >> 8) & 255u) + ((w1 >> 16) & 255u) + (w1 >> 24);
        s += (w2 & 255u) + ((w2 >> 8) & 255u) + ((w2 >> 16) & 255u) + (w2 >> 24);
        c[k] = s;
    }

    // ---- reduce: total valid, min/max of top-16 depth bits (weighted) ----
    unsigned tot = 0, mn = 0xFFFFFFFFu, mx = 0;
    #pragma unroll
    for (int k = 0; k < GPT; ++k) {
        tot += c[k];
        if (c[k]) {
            unsigned hi = d[k] >> 16;
            mn = min(mn, hi);
            mx = max(mx, hi);
        }
    }
    for (int m = 1; m < 64; m <<= 1) {
        tot += (unsigned)__shfl_xor((int)tot, m);
        mn = min(mn, (unsigned)__shfl_xor((int)mn, m));
        mx = max(mx, (unsigned)__shfl_xor((int)mx, m));
    }
    if (lane == 0) { s_wT[wid] = tot; s_wMn[wid] = mn; s_wMx[wid] = mx; }
    __syncthreads();
    if (tid == 0) {
        unsigned t2 = 0, m2 = 0xFFFFFFFFu, x2 = 0;
        for (int w = 0; w < 16; ++w) {
            t2 += s_wT[w]; m2 = min(m2, s_wMn[w]); x2 = max(x2, s_wMx[w]);
        }
        s_tot = t2; s_mn = m2; s_mx = x2;
        s_found = 0;
    }
    __syncthreads();
    unsigned K = (unsigned)maxBlocksPtr[0];
    tot = s_tot; mn = s_mn; mx = s_mx;

    if (tot <= K) {                         // keep all valid
        if (tid == 0) {
            sel[0] = 0xFFFFFFFFu;
            sel[1] = 0x7FFFFFFFu;
            *nTiedG = 0u;
        }
        return;                             // uniform exit
    }

    // ---- pass A: 16-bit windowed histogram, chunks of WBINS ----
    unsigned remK = K;
    unsigned prefix = 0;
    unsigned span = mx - mn + 1u;
    unsigned nchunks = (span + WBINS - 1u) / WBINS;
    for (unsigned ch = 0; ch < nchunks; ++ch) {
        unsigned base = mn + ch * WBINS;
        #pragma unroll
        for (int j = 0; j < BPT; ++j) s_h[tid + j * K2T] = 0;
        __syncthreads();
        #pragma unroll
        for (int k = 0; k < GPT; ++k) {
            if (c[k]) {
                unsigned hi = d[k] >> 16;
                if (hi >= base && hi < base + WBINS)
                    atomicAdd(&s_h[hi - base], c[k]);
            }
        }
        __syncthreads();
        unsigned ps = 0;
        #pragma unroll
        for (int j = 0; j < BPT; ++j) ps += s_h[tid * BPT + j];
        // hierarchical inclusive scan of ps over tid order
        unsigned iw = wave_incl_scan(ps, lane);
        if (lane == 63) s_w[wid] = iw;
        __syncthreads();
        if (wid == 0) {
            unsigned wv = (lane < 16) ? s_w[lane] : 0u;
            unsigned wiw = wave_incl_scan(wv, lane);
            if (lane < 16) s_w[lane] = wiw - wv;   // exclusive wave offset
            if (lane == 15) s_chTot = wiw;         // chunk total
        }
        __syncthreads();
        unsigned incl = iw + s_w[wid];
        unsigned chunkTot = s_chTot;
        unsigned excl = incl - ps;
        if (remK <= chunkTot && excl < remK && remK <= incl) {
            unsigned cum = excl;
            #pragma unroll
            for (int j = 0; j < BPT; ++j) {
                unsigned hv = s_h[tid * BPT + j];
                if (cum < remK && remK <= cum + hv) {
                    s_found  = 1u;
                    s_prefix = base + (unsigned)(tid * BPT + j);
                    s_remK   = remK - cum;
                }
                cum += hv;
            }
        }
        __syncthreads();
        if (s_found) { prefix = s_prefix; remK = s_remK; break; }
        remK -= chunkTot;                   // uniform
        __syncthreads();
    }

    // ---- passes B, C: 8-bit refine (bits 15..8 then 7..0) ----
    for (int p = 0; p < 2; ++p) {
        int matchShift = (p == 0) ? 16 : 8;
        int digitShift = (p == 0) ? 8 : 0;
        if (tid < 256) s_h[tid] = 0;
        __syncthreads();
        #pragma unroll
        for (int k = 0; k < GPT; ++k) {
            if (c[k] && (d[k] >> matchShift) == prefix)
                atomicAdd(&s_h[(d[k] >> digitShift) & 255u], c[k]);
        }
        __syncthreads();
        unsigned ps = (tid < 256) ? s_h[tid] : 0u;
        unsigned iw = wave_incl_scan(ps, lane);
        if (lane == 63) s_w[wid] = iw;
        __syncthreads();
        if (wid == 0) {
            unsigned wv = (lane < 16) ? s_w[lane] : 0u;
            unsigned wiw = wave_incl_scan(wv, lane);
            if (lane < 16) s_w[lane] = wiw - wv;
        }
        __syncthreads();
        unsigned incl = iw + s_w[wid];
        unsigned excl = incl - ps;
        if (excl < remK && remK <= incl) {   // unique crossing thread (tid<256)
            s_prefix = (prefix << 8) | (unsigned)tid;
            s_remK   = remK - excl;
        }
        __syncthreads();
        prefix = s_prefix; remK = s_remK;
        __syncthreads();
    }
    unsigned T = prefix;                     // final threshold depth bits
    unsigned R = remK;                       // quota at exactly T

    // ---- tied groups: list (sorted), per-x valid prefix ----
    if (tid == 0) s_n = 0;
    for (int x = tid; x < GX; x += K2T) s_cntX[x] = 0;
    __syncthreads();
    #pragma unroll
    for (int k = 0; k < GPT; ++k) {
        if (d[k] == T) {
            int idx = atomicAdd(&s_n, 1);
            if (idx < 256) s_list[idx] = (unsigned)(tid + k * K2T);
        }
    }
    __syncthreads();
    int n = min(s_n, 256);
    if (tid == 0) {
        for (int a = 1; a < n; ++a) {        // insertion sort (n tiny)
            unsigned v = s_list[a];
            int b = a - 1;
            while (b >= 0 && s_list[b] > v) { s_list[b + 1] = s_list[b]; --b; }
            s_list[b + 1] = v;
        }
    }
    __syncthreads();
    int pairs = GX * n;
    for (int pr = tid; pr < pairs; pr += K2T) {
        int x = pr / n;
        int s = pr - x * n;
        float occ;
        if (voxel_valid(x, (int)s_list[s], occL, s_mvp, &occ))
            atomicAdd(&s_cntX[x], 1u);
    }
    __syncthreads();
    if (tid == 0) {
        unsigned run = 0;
        for (int x = 0; x < GX; ++x) { tiedPrefX[x] = run; run += s_cntX[x]; }
        *nTiedG = (unsigned)n;
        sel[0] = T;
        sel[1] = R;
    }
    if (tid < n) tiedList[tid] = s_list[tid];
}

__global__ __launch_bounds__(256) void k_out(
    const float* __restrict__ occL,
    const float* __restrict__ matL,
    const float* __restrict__ mvp,
    const unsigned* __restrict__ depthBits,
    const unsigned* __restrict__ sel,
    const unsigned* __restrict__ tiedList,
    const unsigned* __restrict__ tiedPrefX,
    const unsigned* __restrict__ nTiedPtr,
    float* __restrict__ out)
{
    int i = blockIdx.x * 256 + threadIdx.x;
    if (i >= NVOX) return;
    int x = i / GRP;
    int g = i - x * GRP;

    float occ;
    bool valid = voxel_valid(x, g, occL, mvp, &occ);
    bool keep = false;
    if (valid) {
        unsigned T  = sel[0];
        unsigned db = depthBits[g];
        if (db < T) {
            keep = true;
        } else if (db == T) {
            unsigned R = sel[1];
            unsigned rank = tiedPrefX[x];
            int n = (int)*nTiedPtr;
            for (int s = 0; s < n; ++s) {
                unsigned gs = tiedList[s];
                if (gs >= (unsigned)g) break;
                float o2;
                if (voxel_valid(x, (int)gs, occL, mvp, &o2)) ++rank;
            }
            keep = rank < R;
        }
    }

    f4 o0 = (f4)(0.0f);
    f4 o1 = (f4)(0.0f);
    if (keep) {
        const f4* mp = reinterpret_cast<const f4*>(matL) + (size_t)i * 2;
        f4 a = __builtin_nontemporal_load(mp);
        f4 b = __builtin_nontemporal_load(mp + 1);
        float mx = fmaxf(fmaxf(fmaxf(a[0], a[1]), fmaxf(a[2], a[3])),
                         fmaxf(fmaxf(b[0], b[1]), fmaxf(b[2], b[3])));
        float e0 = expf(a[0] - mx), e1 = expf(a[1] - mx), e2 = expf(a[2] - mx), e3 = expf(a[3] - mx);
        float e4 = expf(b[0] - mx), e5 = expf(b[1] - mx), e6 = expf(b[2] - mx), e7 = expf(b[3] - mx);
        float s = ((e0 + e1) + (e2 + e3)) + ((e4 + e5) + (e6 + e7));
        float inv = occ / s;
        o0[0] = e0 * inv; o0[1] = e1 * inv; o0[2] = e2 * inv; o0[3] = e3 * inv;
        o1[0] = e4 * inv; o1[1] = e5 * inv; o1[2] = e6 * inv; o1[3] = e7 * inv;
    }
    f4* op = reinterpret_cast<f4*>(out) + (size_t)i * 2;
    __builtin_nontemporal_store(o0, op);
    __builtin_nontemporal_store(o1, op + 1);
}

extern "C" void kernel_launch(void* const* d_in, const int* in_sizes, int n_in,
                              void* d_out, int out_size, void* d_ws, size_t ws_size,
                              hipStream_t stream)
{
    const float* occL = (const float*)d_in[0];
    const float* matL = (const float*)d_in[1];
    const float* view = (const float*)d_in[2];
    const float* proj = (const float*)d_in[3];
    const int*   mb   = (const int*)d_in[4];

    char* ws = (char*)d_ws;
    float*         mvp      = (float*)(ws + WS_MVP);
    unsigned*      depthB   = (unsigned*)(ws + WS_DEPTH);
    unsigned char* cnt8     = (unsigned char*)(ws + WS_CNT8);
    unsigned*      sel      = (unsigned*)(ws + WS_SEL);
    unsigned*      tiedList = (unsigned*)(ws + WS_TLIST);
    unsigned*      tiedPref = (unsigned*)(ws + WS_TPREF);
    unsigned*      nTied    = (unsigned*)(ws + WS_NTIED);

    k_prep_count<<<NXC * GBLK, 256, 0, stream>>>(view, proj, occL, mvp, depthB, cnt8);
    k_select<<<1, K2T, 0, stream>>>(view, proj, occL, depthB, cnt8, mb,
                                    sel, tiedList, tiedPref, nTied);
    k_out<<<NVOX / 256, 256, 0, stream>>>(occL, matL, mvp, depthB, sel,
                                          tiedList, tiedPref, nTied, (float*)d_out);
}